// Round 1
// baseline (818.154 us; speedup 1.0000x reference)
//
#include <hip/hip_runtime.h>

#define N_NODES 100000
#define N_EDGES 3200000
#define DIM 128
#define NBUCK 391        // ceil(100000/256) buckets of 256 nodes (dst>>8)
#define NBP 392          // padded
#define EB_BLOCKS 782    // ceil(3.2M / 4096) edge blocks (4096 edges/block)

// ---------------- helpers ----------------

__device__ __forceinline__ unsigned rne_bf16(float f) {
    unsigned u = __builtin_bit_cast(unsigned, f);
    return (u + 0x7FFFu + ((u >> 16) & 1u)) >> 16;
}
__device__ __forceinline__ float bf16lo(unsigned u) {
    return __builtin_bit_cast(float, u << 16);
}
__device__ __forceinline__ float bf16hi(unsigned u) {
    return __builtin_bit_cast(float, u & 0xFFFF0000u);
}

// ---------------- CSR build: bucket counting sort ----------------
// Device-scope atomics execute at the address's HOME slice (memory-side);
// cut global atomics 12.8M -> ~0.6M via coarse buckets + LDS ranking.

// B1: per-block LDS hist of 4096 edges into 392 buckets; 1 global atomic per (block,bucket)
__global__ __launch_bounds__(256) void bhist_k(const int* __restrict__ dst,
                                               int* __restrict__ bucketTotal) {
    __shared__ int h[NBP];
    int tid = threadIdx.x;
    for (int i = tid; i < NBP; i += 256) h[i] = 0;
    __syncthreads();
#pragma unroll
    for (int c = 0; c < 4; c++) {
        int e = blockIdx.x * 4096 + c * 1024 + tid * 4;
        if (e < N_EDGES) {
            int4 d4 = ((const int4*)dst)[e >> 2];
            atomicAdd(&h[d4.x >> 8], 1);
            atomicAdd(&h[d4.y >> 8], 1);
            atomicAdd(&h[d4.z >> 8], 1);
            atomicAdd(&h[d4.w >> 8], 1);
        }
    }
    __syncthreads();
    for (int i = tid; i < NBP; i += 256)
        if (h[i] > 0) atomicAdd(&bucketTotal[i], h[i]);
}

// B2: exclusive scan of 392 bucket totals -> bucketBase[0..392], init cursors
__global__ __launch_bounds__(512) void bscan_k(const int* __restrict__ bucketTotal,
                                               int* __restrict__ bucketBase,
                                               int* __restrict__ bucketCursor) {
    __shared__ int tmp[512];
    int tid = threadIdx.x;
    int v = (tid < NBP) ? bucketTotal[tid] : 0;
    tmp[tid] = v;
    __syncthreads();
    for (int off = 1; off < 512; off <<= 1) {
        int x = tmp[tid];
        if (tid >= off) x += tmp[tid - off];
        __syncthreads();
        tmp[tid] = x;
        __syncthreads();
    }
    if (tid < NBP) {
        int excl = tmp[tid] - v;
        bucketBase[tid] = excl;
        bucketCursor[tid] = excl;
        if (tid == NBP - 1) bucketBase[NBP] = tmp[tid];
    }
}

// B3: re-hist per block, reserve per-bucket runs (1 global atomic per block,bucket),
// scatter (src,dst) pairs into bucket regions via LDS cursors
__global__ __launch_bounds__(256) void bscatter_k(const int* __restrict__ src,
                                                  const int* __restrict__ dst,
                                                  int* __restrict__ bucketCursor,
                                                  int2* __restrict__ ebuf) {
    __shared__ int h[NBP];
    __shared__ int lcur[NBP];
    int tid = threadIdx.x;
    for (int i = tid; i < NBP; i += 256) h[i] = 0;
    __syncthreads();
#pragma unroll
    for (int c = 0; c < 4; c++) {
        int e = blockIdx.x * 4096 + c * 1024 + tid * 4;
        if (e < N_EDGES) {
            int4 d4 = ((const int4*)dst)[e >> 2];
            atomicAdd(&h[d4.x >> 8], 1);
            atomicAdd(&h[d4.y >> 8], 1);
            atomicAdd(&h[d4.z >> 8], 1);
            atomicAdd(&h[d4.w >> 8], 1);
        }
    }
    __syncthreads();
    for (int i = tid; i < NBP; i += 256)
        lcur[i] = (h[i] > 0) ? atomicAdd(&bucketCursor[i], h[i]) : 0;
    __syncthreads();
#pragma unroll
    for (int c = 0; c < 4; c++) {
        int e = blockIdx.x * 4096 + c * 1024 + tid * 4;
        if (e < N_EDGES) {
            int4 d4 = ((const int4*)dst)[e >> 2];
            int4 s4 = ((const int4*)src)[e >> 2];
            int p0 = atomicAdd(&lcur[d4.x >> 8], 1);
            int p1 = atomicAdd(&lcur[d4.y >> 8], 1);
            int p2 = atomicAdd(&lcur[d4.z >> 8], 1);
            int p3 = atomicAdd(&lcur[d4.w >> 8], 1);
            ebuf[p0] = make_int2(s4.x, d4.x);
            ebuf[p1] = make_int2(s4.y, d4.y);
            ebuf[p2] = make_int2(s4.z, d4.z);
            ebuf[p3] = make_int2(s4.w, d4.w);
        }
    }
}

// B4: one block per bucket (256 nodes, ~8.2K edges): LDS count, scan -> offsets,
// LDS-cursor rank -> final csr. Zero global atomics.
__global__ __launch_bounds__(256) void bfinal_k(const int2* __restrict__ ebuf,
                                                const int* __restrict__ bucketBase,
                                                int* __restrict__ offsets,
                                                int* __restrict__ csr) {
    __shared__ int h[256];
    __shared__ int sc[256];
    int tid = threadIdx.x;
    int b = blockIdx.x;
    int s = bucketBase[b], e = bucketBase[b + 1];
    h[tid] = 0;
    __syncthreads();
    for (int idx = s + tid; idx < e; idx += 256) {
        int2 ed = ebuf[idx];
        atomicAdd(&h[ed.y & 255], 1);
    }
    __syncthreads();
    sc[tid] = h[tid];
    __syncthreads();
    for (int off = 1; off < 256; off <<= 1) {
        int x = sc[tid];
        if (tid >= off) x += sc[tid - off];
        __syncthreads();
        sc[tid] = x;
        __syncthreads();
    }
    int excl = sc[tid] - h[tid];
    int node = b * 256 + tid;
    if (node < N_NODES) offsets[node] = s + excl;
    if (b == 0 && tid == 0) offsets[N_NODES] = N_EDGES;
    __syncthreads();
    h[tid] = s + excl;   // reuse as cursor
    __syncthreads();
    for (int idx = s + tid; idx < e; idx += 256) {
        int2 ed = ebuf[idx];
        int pos = atomicAdd(&h[ed.y & 255], 1);
        csr[pos] = ed.x;
    }
}

// ---------------- per-layer compute ----------------

// G[r][c] = sum_k H[r][k] * W[k][c]; output stored as bf16 (RNE) for the gather
// K-loop stepped by 4 with explicit float4 LDS reads: 256 ds_read_b128/thread
// instead of 1024 ds_read_b32 around the same 4096 FMAs.
__global__ __launch_bounds__(256) void gemm_k(const float* __restrict__ H,
                                              const float* __restrict__ W,
                                              unsigned short* __restrict__ G) {
    __shared__ float hs[64][128];
    int tid = threadIdx.x;
    int rowBase = blockIdx.x * 64;
    for (int i = tid; i < 64 * 32; i += 256) {
        int r = i >> 5, c4 = i & 31;
        int row = rowBase + r;
        float4 v = make_float4(0.f, 0.f, 0.f, 0.f);
        if (row < N_NODES) v = ((const float4*)(H + (size_t)row * DIM))[c4];
        ((float4*)&hs[r][0])[c4] = v;
    }
    __syncthreads();

    int tx = tid & 31, ty = tid >> 5;
    int c0 = tx * 4, r0 = ty * 8;
    float4 acc[8];
#pragma unroll
    for (int r = 0; r < 8; r++) acc[r] = make_float4(0.f, 0.f, 0.f, 0.f);

    for (int k = 0; k < DIM; k += 4) {
        float4 w0 = *(const float4*)(W + (size_t)k * DIM + c0);
        float4 w1 = *(const float4*)(W + (size_t)(k + 1) * DIM + c0);
        float4 w2 = *(const float4*)(W + (size_t)(k + 2) * DIM + c0);
        float4 w3 = *(const float4*)(W + (size_t)(k + 3) * DIM + c0);
#pragma unroll
        for (int r = 0; r < 8; r++) {
            float4 h4 = *(const float4*)&hs[r0 + r][k];
            acc[r].x += h4.x * w0.x + h4.y * w1.x + h4.z * w2.x + h4.w * w3.x;
            acc[r].y += h4.x * w0.y + h4.y * w1.y + h4.z * w2.y + h4.w * w3.y;
            acc[r].z += h4.x * w0.z + h4.y * w1.z + h4.z * w2.z + h4.w * w3.z;
            acc[r].w += h4.x * w0.w + h4.y * w1.w + h4.z * w2.w + h4.w * w3.w;
        }
    }
#pragma unroll
    for (int r = 0; r < 8; r++) {
        int row = rowBase + r0 + r;
        if (row < N_NODES) {
            uint2 pk;
            pk.x = rne_bf16(acc[r].x) | (rne_bf16(acc[r].y) << 16);
            pk.y = rne_bf16(acc[r].z) | (rne_bf16(acc[r].w) << 16);
            *(uint2*)(G + (size_t)row * DIM + c0) = pk;
        }
    }
}

// Quad-gather: 4 edges per wave-instruction. quarter = lane>>4 picks the edge,
// q = lane&15 picks the 16-byte slice of the 256 B bf16 row (uint4 = 8 bf16).
// Index fetch: ONE dword load per quad (4 distinct addrs, 16-way broadcast,
// L1-hit) instead of one per lane-pair. Halves VMEM instruction count vs the
// uint2 version and doubles bytes per gather instruction.
__device__ __forceinline__ void accum8(float* acc, uint4 v) {
    acc[0] += bf16lo(v.x); acc[1] += bf16hi(v.x);
    acc[2] += bf16lo(v.y); acc[3] += bf16hi(v.y);
    acc[4] += bf16lo(v.z); acc[5] += bf16hi(v.z);
    acc[6] += bf16lo(v.w); acc[7] += bf16hi(v.w);
}

template <int P>
__device__ __forceinline__ void gather_quads(const unsigned short* __restrict__ G,
                                             const int* __restrict__ cl, int i,
                                             int q, int quarter, float* acc) {
    uint4 v[P];
#pragma unroll
    for (int p = 0; p < P; p++) {
        int idx = cl[i + 4 * p + quarter];
        v[p] = *(const uint4*)(G + (size_t)idx * DIM + q * 8);
    }
#pragma unroll
    for (int p = 0; p < P; p++) accum8(acc, v[p]);
}

// out[i] = (1+eps)*G[i] + sum_{in-edges} G[csr[e]] + b   (G bf16, out f32)
// One wave/node; 4 rows in flight per gather instr; 32 edges (8 uint4 loads)
// outstanding in main loop; hierarchical 16/8/4/partial tail (avg degree 32).
__global__ __launch_bounds__(256) void agg_k(const unsigned short* __restrict__ G,
                                             const int* __restrict__ off,
                                             const int* __restrict__ csr,
                                             const float* __restrict__ bias,
                                             const float* __restrict__ epsp,
                                             float* __restrict__ out) {
    int lane = threadIdx.x & 63;
    int node = blockIdx.x * 4 + (threadIdx.x >> 6);
    int quarter = lane >> 4;   // 0..3: which edge of the quad
    int q = lane & 15;         // 0..15: cols 8q..8q+7 of the row
    float e1 = 1.0f + epsp[0];

    float acc[8] = {0.f, 0.f, 0.f, 0.f, 0.f, 0.f, 0.f, 0.f};
    int s = off[node], e = off[node + 1];
    int n = e - s;
    const int* cl = csr + s;
    int i = 0;
    for (; i + 32 <= n; i += 32) gather_quads<8>(G, cl, i, q, quarter, acc);
    if (i + 16 <= n) { gather_quads<4>(G, cl, i, q, quarter, acc); i += 16; }
    if (i + 8 <= n)  { gather_quads<2>(G, cl, i, q, quarter, acc); i += 8; }
    if (i + 4 <= n)  { gather_quads<1>(G, cl, i, q, quarter, acc); i += 4; }
    if (i < n) {       // 1..3 leftover edges: clamp index, mask accumulate
        int ei = i + quarter;
        int idx = cl[ei < n ? ei : n - 1];
        uint4 v = *(const uint4*)(G + (size_t)idx * DIM + q * 8);
        if (ei < n) accum8(acc, v);
    }
    // reduce the 4 quarter-copies of each column block
#pragma unroll
    for (int j = 0; j < 8; j++) acc[j] += __shfl_xor(acc[j], 16);
#pragma unroll
    for (int j = 0; j < 8; j++) acc[j] += __shfl_xor(acc[j], 32);

    if (lane < 32) {   // lanes 0-15 write cols 8q..8q+3, lanes 16-31 cols 8q+4..8q+7
        int hh = quarter & 1;
        int col = q * 8 + hh * 4;
        // static-select to keep acc in registers (no runtime array indexing)
        float a0 = (hh == 0) ? acc[0] : acc[4];
        float a1 = (hh == 0) ? acc[1] : acc[5];
        float a2 = (hh == 0) ? acc[2] : acc[6];
        float a3 = (hh == 0) ? acc[3] : acc[7];
        uint2 sv = *(const uint2*)(G + (size_t)node * DIM + col);
        float4 bb = *(const float4*)(bias + col);
        float4 r;
        r.x = a0 + e1 * bf16lo(sv.x) + bb.x;
        r.y = a1 + e1 * bf16hi(sv.x) + bb.y;
        r.z = a2 + e1 * bf16lo(sv.y) + bb.z;
        r.w = a3 + e1 * bf16hi(sv.y) + bb.w;
        *(float4*)(out + (size_t)node * DIM + col) = r;
    }
}

// ---------------- launch ----------------

extern "C" void kernel_launch(void* const* d_in, const int* in_sizes, int n_in,
                              void* d_out, int out_size, void* d_ws, size_t ws_size,
                              hipStream_t stream) {
    const float* feats = (const float*)d_in[0];
    const int* esrc = (const int*)d_in[1];
    const int* edst = (const int*)d_in[2];
    const float* Wm[3] = {(const float*)d_in[3], (const float*)d_in[6], (const float*)d_in[9]};
    const float* Bv[3] = {(const float*)d_in[4], (const float*)d_in[7], (const float*)d_in[10]};
    const float* Ev[3] = {(const float*)d_in[5], (const float*)d_in[8], (const float*)d_in[11]};
    float* out = (float*)d_out;

    char* ws = (char*)d_ws;
    unsigned short* bufG = (unsigned short*)(ws);     // 25,600,000 B : g = h @ W (bf16)
    int* csr        = (int*)(ws + 25600000);          // 12,800,000 B
    int2* ebuf      = (int2*)(ws + 38400000);         // 25,600,000 B (src,dst) bucketed
    int* offsets    = (int*)(ws + 64000000);          //    400,004 B
    int* bucketTotal= (int*)(ws + 64400128);          //      1,568 B
    int* bucketBase = (int*)(ws + 64401792);          //      1,572 B
    int* bucketCur  = (int*)(ws + 64403456);          //      1,568 B

    // CSR build: bucket counting sort (global atomics ~0.6M vs 12.8M)
    hipMemsetAsync(bucketTotal, 0, NBP * sizeof(int), stream);
    bhist_k<<<EB_BLOCKS, 256, 0, stream>>>(edst, bucketTotal);
    bscan_k<<<1, 512, 0, stream>>>(bucketTotal, bucketBase, bucketCur);
    bscatter_k<<<EB_BLOCKS, 256, 0, stream>>>(esrc, edst, bucketCur, ebuf);
    bfinal_k<<<NBUCK, 256, 0, stream>>>(ebuf, bucketBase, offsets, csr);

    // 3 GIN layers: g = h @ W  (bufG, bf16);  h' = (1+eps)g + agg(g) + b  (d_out, f32)
    const float* h = feats;
    for (int l = 0; l < 3; l++) {
        gemm_k<<<(N_NODES + 63) / 64, 256, 0, stream>>>(h, Wm[l], bufG);
        agg_k<<<N_NODES / 4, 256, 0, stream>>>(bufG, offsets, csr, Bv[l], Ev[l], out);
        h = out;
    }
}